// Round 7
// baseline (227.766 us; speedup 1.0000x reference)
//
#include <hip/hip_runtime.h>

#define QMAX 127.0f

typedef int v4i __attribute__((ext_vector_type(4)));

__device__ __forceinline__ void gload_lds16(const void* g, void* l) {
  __builtin_amdgcn_global_load_lds(
      (const __attribute__((address_space(1))) void*)g,
      (__attribute__((address_space(3))) void*)l, 16, 0, 0);
}

// ---------------- merged prep: pack W0/W1/W2 + quantize x (1 launch) --------
__device__ __forceinline__ void pack_body(const int* __restrict__ W,
                                          signed char* __restrict__ W8,
                                          int* __restrict__ bias,
                                          unsigned lblk, int kshift) {
  unsigned t = lblk * 256u + threadIdx.x;
  unsigned row = t >> kshift;
  unsigned j = t & ((1u << kshift) - 1u);
  unsigned K = 4u << kshift;
  size_t srcBase = (size_t)row * (size_t)(K + 1) + (size_t)j * 4;
  int c0 = W[srcBase + 0], c1 = W[srcBase + 1], c2 = W[srcBase + 2], c3 = W[srcBase + 3];
  unsigned packed = (unsigned)(c0 & 0xff) | ((unsigned)(c1 & 0xff) << 8) |
                    ((unsigned)(c2 & 0xff) << 16) | ((unsigned)(c3 & 0xff) << 24);
  reinterpret_cast<unsigned*>(W8)[t] = packed;
  if (j == 0) bias[row] = W[(size_t)row * (K + 1) + K];
}

__global__ void prep_kernel(const float* __restrict__ x,
                            signed char* __restrict__ qa0,
                            const float* __restrict__ pAin,
                            const int* __restrict__ W0, signed char* __restrict__ W0p, int* __restrict__ b0,
                            const int* __restrict__ W1, signed char* __restrict__ W1p, int* __restrict__ b1,
                            const int* __restrict__ W2, signed char* __restrict__ W2p, int* __restrict__ b2) {
  unsigned blk = blockIdx.x;
  if (blk < 4096u) {
    pack_body(W0, W0p, b0, blk, 8);
  } else if (blk < 20480u) {
    pack_body(W1, W1p, b1, blk - 4096u, 10);
  } else if (blk < 24576u) {
    pack_body(W2, W2p, b2, blk - 20480u, 10);
  } else {
    unsigned t = (blk - 24576u) * 256u + threadIdx.x;
    float s = QMAX / pAin[0];
    float4 v = reinterpret_cast<const float4*>(x)[t];
    int q0 = (int)fminf(fmaxf(rintf(v.x * s), -QMAX), QMAX);
    int q1 = (int)fminf(fmaxf(rintf(v.y * s), -QMAX), QMAX);
    int q2 = (int)fminf(fmaxf(rintf(v.z * s), -QMAX), QMAX);
    int q3 = (int)fminf(fmaxf(rintf(v.w * s), -QMAX), QMAX);
    unsigned packed = (unsigned)(q0 & 0xff) | ((unsigned)(q1 & 0xff) << 8) |
                      ((unsigned)(q2 & 0xff) << 16) | ((unsigned)(q3 & 0xff) << 24);
    reinterpret_cast<unsigned*>(qa0)[t] = packed;
  }
}

// =====================================================================
// 256x256-tile int8 GEMM, A-OPERAND IN REGISTERS (global->VGPR, no LDS),
// B double-buffered in LDS (64 KiB). Rationale: 4 prior schedules all hit
// the same ~4950 cyc/K-tile = LDS-port + MFMA SUM (no overlap across a
// barrier-locked WG). Removing A from LDS cuts port demand to 96 KB/tile
// (reads 64K + writes 32K), far under the MFMA shadow; A-loads are
// barrier-free and pipeline via counted vmcnt.
// FIFO audit (steady state entering tile t: [A-k0(t):8]):
//   +stageB(t+1):4  +A-k1(t):8          -> vmcnt(12) drains A-k0(t)
//   MFMA(k0); +A-k0(t+1):8              -> vmcnt(8)  drains stage+A-k1
//   MFMA(k1); BARRIER (B buf swap)
// lgkmcnt(0) before each MFMA covers the 4 B ds_reads (WAR on B bufs:
// reads drained pre-barrier, stage lands post-barrier).
// =====================================================================

#define FENCE() asm volatile("" ::: "memory")
#define BARRIER()                      \
  do {                                 \
    FENCE();                           \
    __builtin_amdgcn_s_barrier();      \
    FENCE();                           \
  } while (0)
#define LGK0() asm volatile("s_waitcnt lgkmcnt(0)" ::: "memory")
#define VMC(n) asm volatile("s_waitcnt vmcnt(" #n ")" ::: "memory")

#define STAGE_B(bf, h, t)                                                     \
  do {                                                                        \
    const signed char* _g = gB + (size_t)((h) * 128) * K + (size_t)(t) * 128; \
    signed char* _l = ldsB + (bf) * 32768 + (h) * 16384 + ldsThr;             \
    gload_lds16(_g, _l);                                                      \
    gload_lds16(_g + (size_t)8 * K, _l + 1024);                               \
  } while (0)

// 8 global_load_dwordx4: all A m-frags for tile t, k-half kk -> dst[0..7]
// (per-lane addr = MFMA A-fragment layout directly; no LDS, no swizzle)
#define GLA8(t, kk, dst)                                                      \
  do {                                                                        \
    _Pragma("unroll") for (int m = 0; m < 8; ++m)                             \
      dst[m] = *(const v4i*)(gAf + (size_t)(m * 16) * K +                     \
                             (size_t)(t) * 128 + (kk) * 64);                  \
  } while (0)

// 4 ds_read_b128: all B n-frags for k-half kk -> bK[0..3]
#define LDB4(bf, kk)                                                          \
  do {                                                                        \
    _Pragma("unroll") for (int n = 0; n < 4; ++n) {                           \
      int row = wn * 64 + n * 16 + l15;                                       \
      int off = ((kk) * 64 + hi * 16) ^ ((l15 & 7) << 4);                     \
      bK[n] = *(const v4i*)(ldsB + (bf) * 32768 + row * 128 + off);           \
    }                                                                         \
  } while (0)

// 32 MFMA: all m x all n for one k-half
#define MFMA32(aset)                                                          \
  do {                                                                        \
    __builtin_amdgcn_s_setprio(1);                                            \
    _Pragma("unroll") for (int m = 0; m < 8; ++m)                             \
    _Pragma("unroll") for (int n = 0; n < 4; ++n)                             \
      acc[m][n] = __builtin_amdgcn_mfma_i32_16x16x64_i8(                      \
          aset[m], bK[n], acc[m][n], 0, 0, 0);                                \
    __builtin_amdgcn_s_setprio(0);                                            \
  } while (0)

__global__ __launch_bounds__(512, 2)
void qgemm256_kernel(const signed char* __restrict__ A,
                     const signed char* __restrict__ Bw,
                     const int* __restrict__ bias,
                     signed char* __restrict__ O,
                     int N, int K, int nbn,
                     const float* __restrict__ pAin,
                     const float* __restrict__ pAw,
                     const float* __restrict__ pAnext) {
  extern __shared__ signed char lds[];
  signed char* ldsB = lds;   // B only: buf0 [0,32K), buf1 [32K,64K)

  const int nwg = gridDim.x, bid = blockIdx.x, per = nwg >> 3;
  const int swz = (bid & 7) * per + (bid >> 3);
  const int brow = swz / nbn, bcol = swz - brow * nbn;
  const int browBase = brow << 8, bcolBase = bcol << 8;

  const int tid = threadIdx.x;
  const int lane = tid & 63, l15 = lane & 15, hi = lane >> 4;
  const int wid = tid >> 6, wm = wid >> 2, wn = wid & 3;

  // B staging thread-constants (involution swizzle, same as prior rounds)
  const int rloc = (wid << 4) + (lane >> 3);
  const int csrc = (lane & 7) ^ ((lane >> 3) & 7);
  const signed char* gB = Bw + (size_t)(bcolBase + rloc) * K + csrc * 16;
  const int ldsThr = (wid << 11) + lane * 16;

  // A register-load base: per-lane fragment address (row = l15, bytes = hi*16)
  const signed char* gAf =
      A + (size_t)(browBase + wm * 128 + l15) * K + hi * 16;

  v4i acc[8][4] = {};
  v4i aK0[8], aK1[8], bK[4];

  const int nk = K >> 7, niter = nk >> 1, nkm = nk - 1;

  // prologue: stage B(0)->buf0 (4 vmem), load A-k0(0) (8 vmem);
  // vmcnt(8) drains the stage, leaves A-k0 in flight.
  STAGE_B(0, 0, 0); STAGE_B(0, 1, 0);
  GLA8(0, 0, aK0);
  VMC(8);
  BARRIER();

#pragma unroll 1
  for (int i = 0; i < niter; ++i) {
    const int tC = 2 * i;               // even tile -> buf0
    const int tO = 2 * i + 1;           // odd tile  -> buf1
    const int tN = (2 * i + 2) & nkm;   // next even (wraps once, harmless)
    // ======== tile tC (B in buf0) ========
    STAGE_B(1, 0, tO); STAGE_B(1, 1, tO);   // 4 vmem -> buf1
    GLA8(tC, 1, aK1);                        // 8 vmem
    LDB4(0, 0);                              // 4 ds
    VMC(12);                                 // A-k0(tC) ready
    LGK0();                                  // B-k0 ready
    MFMA32(aK0);
    GLA8(tO, 0, aK0);                        // 8 vmem (next tile's k0)
    LDB4(0, 1);                              // 4 ds
    VMC(8);                                  // stage(tO)+A-k1 ready
    LGK0();
    MFMA32(aK1);
    BARRIER();                               // buf1 visible; buf0 reusable
    // ======== tile tO (B in buf1) ========
    STAGE_B(0, 0, tN); STAGE_B(0, 1, tN);
    GLA8(tO, 1, aK1);
    LDB4(1, 0);
    VMC(12);
    LGK0();
    MFMA32(aK0);
    GLA8(tN, 0, aK0);
    LDB4(1, 1);
    VMC(8);
    LGK0();
    MFMA32(aK1);
    BARRIER();
  }

  VMC(0);  // drain orphan prefetches before epilogue

  const float sDeq = (pAw[0] * pAin[0]) / (QMAX * QMAX);
  const float sQ = QMAX / pAnext[0];
#pragma unroll
  for (int nf = 0; nf < 4; ++nf) {
    const int gcol = bcolBase + wn * 64 + nf * 16 + l15;
    const int bv = bias[gcol];
#pragma unroll
    for (int mf = 0; mf < 8; ++mf) {
      const int gr = browBase + wm * 128 + mf * 16 + (hi << 2);
#pragma unroll
      for (int r = 0; r < 4; ++r) {
        float f = (float)(acc[mf][nf][r] + bv) * sDeq;
        f = fmaxf(f, 0.0f);
        float qf = fminf(fmaxf(rintf(f * sQ), -QMAX), QMAX);
        O[(size_t)(gr + r) * N + gcol] = (signed char)(int)qf;
      }
    }
  }
}

// ---------------- 128x128-tile k-split 2-phase int8 GEMM (layer 2) ----------
#define LGK(n) asm volatile("s_waitcnt lgkmcnt(" #n ")" ::: "memory")

#define STG128(bf, t)                                                         \
  do {                                                                        \
    _Pragma("unroll") for (int ii = 0; ii < 4; ++ii) {                        \
      int c = ii * 256 + tid;                                                 \
      int r = c >> 3;                                                         \
      int osrc = ((c & 7) << 4) ^ ((r & 7) << 4);                             \
      gload_lds16(A + (size_t)(browBase + r) * K + ((t) * 128 + osrc),        \
                  ldsA + (bf) * 16384 + c * 16);                              \
      gload_lds16(Bw + (size_t)(bcolBase + r) * K + ((t) * 128 + osrc),       \
                  ldsB + (bf) * 16384 + c * 16);                              \
    }                                                                         \
  } while (0)

#define LDA4_128(bf, kk, dst)                                                 \
  do {                                                                        \
    _Pragma("unroll") for (int m = 0; m < 4; ++m) {                           \
      int row = wr + m * 16 + l15;                                            \
      int off = ((kk) * 64 + hi * 16) ^ ((l15 & 7) << 4);                     \
      dst[m] = *(const v4i*)(ldsA + (bf) * 16384 + row * 128 + off);          \
    }                                                                         \
  } while (0)

#define LDB4_128(bf, kk)                                                      \
  do {                                                                        \
    _Pragma("unroll") for (int n = 0; n < 4; ++n) {                           \
      int row = wc + n * 16 + l15;                                            \
      int off = ((kk) * 64 + hi * 16) ^ ((l15 & 7) << 4);                     \
      bK[n] = *(const v4i*)(ldsB + (bf) * 16384 + row * 128 + off);           \
    }                                                                         \
  } while (0)

#define MFMA16(aset)                                                          \
  do {                                                                        \
    __builtin_amdgcn_s_setprio(1);                                            \
    _Pragma("unroll") for (int m = 0; m < 4; ++m)                             \
    _Pragma("unroll") for (int n = 0; n < 4; ++n)                             \
      acc[m][n] = __builtin_amdgcn_mfma_i32_16x16x64_i8(                      \
          aset[m], bK[n], acc[m][n], 0, 0, 0);                                \
    __builtin_amdgcn_s_setprio(0);                                            \
  } while (0)

__global__ __launch_bounds__(256)
void qgemm_kernel(const signed char* __restrict__ A,
                  const signed char* __restrict__ Bw,
                  const int* __restrict__ bias,
                  float* __restrict__ O,
                  int N, int K, int nbn,
                  const float* __restrict__ pAin,
                  const float* __restrict__ pAw) {
  __shared__ signed char slds[65536];
  signed char* ldsA = slds;            // bufs at 0 / 16K
  signed char* ldsB = slds + 32768;    // bufs at 0 / 16K

  const int nwg = gridDim.x, bid = blockIdx.x, per = nwg >> 3;
  const int swz = (bid & 7) * per + (bid >> 3);
  const int brow = swz / nbn, bcol = swz - brow * nbn;
  const int browBase = brow << 7, bcolBase = bcol << 7;

  const int tid = threadIdx.x;
  const int lane = tid & 63, l15 = lane & 15, hi = lane >> 4;
  const int wid = tid >> 6;
  const int wr = (wid >> 1) << 6, wc = (wid & 1) << 6;

  v4i acc[4][4] = {};
  v4i aK0[4], aK1[4], bK[4];

  const int nk = K >> 7, niter = nk >> 1, nkm = nk - 1;

  STG128(0, 0);
  VMC(0);
  BARRIER();
  LDA4_128(0, 0, aK0);

#pragma unroll 1
  for (int i = 0; i < niter; ++i) {
    const int tO = 2 * i + 1;
    const int tE = (2 * i + 2) & nkm;
    // tile 2i (buf0)
    LGK(4);
    BARRIER();
    STG128(1, tO);
    LDB4_128(0, 0); FENCE(); LDA4_128(0, 1, aK1);
    LGK(4);
    MFMA16(aK0);
    VMC(0);
    BARRIER();
    LDB4_128(0, 1); FENCE(); LDA4_128(1, 0, aK0);
    LGK(4);
    MFMA16(aK1);
    // tile 2i+1 (buf1)
    LGK(4);
    BARRIER();
    STG128(0, tE);
    LDB4_128(1, 0); FENCE(); LDA4_128(1, 1, aK1);
    LGK(4);
    MFMA16(aK0);
    VMC(0);
    BARRIER();
    LDB4_128(1, 1); FENCE(); LDA4_128(0, 0, aK0);
    LGK(4);
    MFMA16(aK1);
  }

  VMC(0);

  const float sDeq = (pAw[0] * pAin[0]) / (QMAX * QMAX);
#pragma unroll
  for (int n = 0; n < 4; ++n) {
    int gcol = bcolBase + wc + n * 16 + l15;
    int bv = bias[gcol];
#pragma unroll
    for (int m = 0; m < 4; ++m) {
      int growb = browBase + wr + m * 16 + (hi << 2);
#pragma unroll
      for (int r = 0; r < 4; ++r) {
        O[(size_t)(growb + r) * N + gcol] = (float)(acc[m][n][r] + bv) * sDeq;
      }
    }
  }
}

extern "C" void kernel_launch(void* const* d_in, const int* in_sizes, int n_in,
                              void* d_out, int out_size, void* d_ws, size_t ws_size,
                              hipStream_t stream) {
  const float* x     = (const float*)d_in[0];
  const float* a_in0 = (const float*)d_in[1];
  const float* a_w0  = (const float*)d_in[2];
  const float* a_in2 = (const float*)d_in[3];
  const float* a_w2  = (const float*)d_in[4];
  const float* a_in4 = (const float*)d_in[5];
  const float* a_w4  = (const float*)d_in[6];
  const int*   W0    = (const int*)d_in[7];
  const int*   W1    = (const int*)d_in[8];
  const int*   W2    = (const int*)d_in[9];
  float* out = (float*)d_out;

  constexpr int B = 4096, IN = 1024, H0 = 4096, H1 = 4096, OUTN = 1024;

  char* ws = (char*)d_ws;
  size_t off = 0;
  auto alloc = [&](size_t sz) {
    char* p = ws + off;
    off += (sz + 255) & ~(size_t)255;
    return p;
  };
  signed char* qa0 = (signed char*)alloc((size_t)B * IN);
  signed char* qa1 = (signed char*)alloc((size_t)B * H0);
  signed char* qa2 = (signed char*)alloc((size_t)B * H1);
  signed char* W0p = (signed char*)alloc((size_t)H0 * IN);
  signed char* W1p = (signed char*)alloc((size_t)H1 * H0);
  signed char* W2p = (signed char*)alloc((size_t)OUTN * H1);
  int* b0 = (int*)alloc((size_t)H0 * 4);
  int* b1 = (int*)alloc((size_t)H1 * 4);
  int* b2 = (int*)alloc((size_t)OUTN * 4);

  hipFuncSetAttribute((const void*)qgemm256_kernel,
                      hipFuncAttributeMaxDynamicSharedMemorySize, 65536);

  // merged prep: pack W0/W1/W2 + quantize x (1 launch, 28672 blocks)
  prep_kernel<<<28672, 256, 0, stream>>>(x, qa0, a_in0,
                                         W0, W0p, b0,
                                         W1, W1p, b1,
                                         W2, W2p, b2);

  // layer 0: [B,IN]x[H0,IN]^T -> qa1 (int8), grid 16x16=256
  qgemm256_kernel<<<(B / 256) * (H0 / 256), 512, 65536, stream>>>(
      qa0, W0p, b0, qa1, H0, IN, H0 / 256, a_in0, a_w0, a_in2);

  // layer 1: [B,H0]x[H1,H0]^T -> qa2 (int8), grid 16x16=256
  qgemm256_kernel<<<(B / 256) * (H1 / 256), 512, 65536, stream>>>(
      qa1, W1p, b1, qa2, H1, H0, H1 / 256, a_in2, a_w2, a_in4);

  // layer 2: [B,H1]x[OUT,H1]^T -> f32 out, 128^2 k-split, grid 32x8=256
  qgemm_kernel<<<(B / 128) * (OUTN / 128), 256, 0, stream>>>(
      qa2, W2p, b2, out, OUTN, H1, OUTN / 128, a_in4, a_w4);
}

// Round 8
// 148.058 us; speedup vs baseline: 1.5384x; 1.5384x over previous
//
#include <hip/hip_runtime.h>

#define QMAX 127.0f

typedef int v4i __attribute__((ext_vector_type(4)));

__device__ __forceinline__ void gload_lds16(const void* g, void* l) {
  __builtin_amdgcn_global_load_lds(
      (const __attribute__((address_space(1))) void*)g,
      (__attribute__((address_space(3))) void*)l, 16, 0, 0);
}

// ---------------- merged prep: pack W0/W1/W2 + quantize x (1 launch) --------
__device__ __forceinline__ void pack_body(const int* __restrict__ W,
                                          signed char* __restrict__ W8,
                                          int* __restrict__ bias,
                                          unsigned lblk, int kshift) {
  unsigned t = lblk * 256u + threadIdx.x;
  unsigned row = t >> kshift;
  unsigned j = t & ((1u << kshift) - 1u);
  unsigned K = 4u << kshift;
  size_t srcBase = (size_t)row * (size_t)(K + 1) + (size_t)j * 4;
  int c0 = W[srcBase + 0], c1 = W[srcBase + 1], c2 = W[srcBase + 2], c3 = W[srcBase + 3];
  unsigned packed = (unsigned)(c0 & 0xff) | ((unsigned)(c1 & 0xff) << 8) |
                    ((unsigned)(c2 & 0xff) << 16) | ((unsigned)(c3 & 0xff) << 24);
  reinterpret_cast<unsigned*>(W8)[t] = packed;
  if (j == 0) bias[row] = W[(size_t)row * (K + 1) + K];
}

__global__ void prep_kernel(const float* __restrict__ x,
                            signed char* __restrict__ qa0,
                            const float* __restrict__ pAin,
                            const int* __restrict__ W0, signed char* __restrict__ W0p, int* __restrict__ b0,
                            const int* __restrict__ W1, signed char* __restrict__ W1p, int* __restrict__ b1,
                            const int* __restrict__ W2, signed char* __restrict__ W2p, int* __restrict__ b2) {
  unsigned blk = blockIdx.x;
  if (blk < 4096u) {
    pack_body(W0, W0p, b0, blk, 8);
  } else if (blk < 20480u) {
    pack_body(W1, W1p, b1, blk - 4096u, 10);
  } else if (blk < 24576u) {
    pack_body(W2, W2p, b2, blk - 20480u, 10);
  } else {
    unsigned t = (blk - 24576u) * 256u + threadIdx.x;
    float s = QMAX / pAin[0];
    float4 v = reinterpret_cast<const float4*>(x)[t];
    int q0 = (int)fminf(fmaxf(rintf(v.x * s), -QMAX), QMAX);
    int q1 = (int)fminf(fmaxf(rintf(v.y * s), -QMAX), QMAX);
    int q2 = (int)fminf(fmaxf(rintf(v.z * s), -QMAX), QMAX);
    int q3 = (int)fminf(fmaxf(rintf(v.w * s), -QMAX), QMAX);
    unsigned packed = (unsigned)(q0 & 0xff) | ((unsigned)(q1 & 0xff) << 8) |
                      ((unsigned)(q2 & 0xff) << 16) | ((unsigned)(q3 & 0xff) << 24);
    reinterpret_cast<unsigned*>(qa0)[t] = packed;
  }
}

// =====================================================================
// 128x128-tile k-split 2-phase int8 GEMM, 256 threads (4 waves, 2Mx2N,
// per-wave 64x64), 64 KiB LDS dbuf -> TWO independent WGs per CU.
// Rationale: every single-WG 256^2 schedule measured = LDS-port + MFMA
// SUM (~63us for 4096^3); independent per-WG barriers let WG-A's MFMA
// cover WG-B's stage/drain. Port cost/MAC is 1.5x the 256^2 tile, but
// overlapped max(port, MFMA) < single-WG sum.
// Loop structure verified correct as r6/r7's gemm2 (absmax 0).
// =====================================================================

#define FENCE() asm volatile("" ::: "memory")
#define BARRIER()                      \
  do {                                 \
    FENCE();                           \
    __builtin_amdgcn_s_barrier();      \
    FENCE();                           \
  } while (0)
#define LGK(n) asm volatile("s_waitcnt lgkmcnt(" #n ")" ::: "memory")
#define VMC(n) asm volatile("s_waitcnt vmcnt(" #n ")" ::: "memory")

#define STG128(bf, t)                                                         \
  do {                                                                        \
    _Pragma("unroll") for (int ii = 0; ii < 4; ++ii) {                        \
      int c = ii * 256 + tid;                                                 \
      int r = c >> 3;                                                         \
      int osrc = ((c & 7) << 4) ^ ((r & 7) << 4);                             \
      gload_lds16(A + (size_t)(browBase + r) * K + ((t) * 128 + osrc),        \
                  ldsA + (bf) * 16384 + c * 16);                              \
      gload_lds16(Bw + (size_t)(bcolBase + r) * K + ((t) * 128 + osrc),       \
                  ldsB + (bf) * 16384 + c * 16);                              \
    }                                                                         \
  } while (0)

#define LDA4_128(bf, kk, dst)                                                 \
  do {                                                                        \
    _Pragma("unroll") for (int m = 0; m < 4; ++m) {                           \
      int row = wr + m * 16 + l15;                                            \
      int off = ((kk) * 64 + hi * 16) ^ ((l15 & 7) << 4);                     \
      dst[m] = *(const v4i*)(ldsA + (bf) * 16384 + row * 128 + off);          \
    }                                                                         \
  } while (0)

#define LDB4_128(bf, kk)                                                      \
  do {                                                                        \
    _Pragma("unroll") for (int n = 0; n < 4; ++n) {                           \
      int row = wc + n * 16 + l15;                                            \
      int off = ((kk) * 64 + hi * 16) ^ ((l15 & 7) << 4);                     \
      bK[n] = *(const v4i*)(ldsB + (bf) * 16384 + row * 128 + off);           \
    }                                                                         \
  } while (0)

#define MFMA16(aset)                                                          \
  do {                                                                        \
    __builtin_amdgcn_s_setprio(1);                                            \
    _Pragma("unroll") for (int m = 0; m < 4; ++m)                             \
    _Pragma("unroll") for (int n = 0; n < 4; ++n)                             \
      acc[m][n] = __builtin_amdgcn_mfma_i32_16x16x64_i8(                      \
          aset[m], bK[n], acc[m][n], 0, 0, 0);                                \
    __builtin_amdgcn_s_setprio(0);                                            \
  } while (0)

// MODE 0: dequant -> relu -> requant int8 (next layer's A). MODE 1: f32 out.
template <int MODE>
__global__ __launch_bounds__(256)
void qgemm_kernel(const signed char* __restrict__ A,
                  const signed char* __restrict__ Bw,
                  const int* __restrict__ bias,
                  void* __restrict__ outp,
                  int N, int K, int nbn,
                  const float* __restrict__ pAin,
                  const float* __restrict__ pAw,
                  const float* __restrict__ pAnext) {
  __shared__ signed char slds[65536];
  signed char* ldsA = slds;            // bufs at 0 / 16K
  signed char* ldsB = slds + 32768;    // bufs at 0 / 16K

  const int nwg = gridDim.x, bid = blockIdx.x, per = nwg >> 3;
  const int swz = (bid & 7) * per + (bid >> 3);
  const int brow = swz / nbn, bcol = swz - brow * nbn;
  const int browBase = brow << 7, bcolBase = bcol << 7;

  const int tid = threadIdx.x;
  const int lane = tid & 63, l15 = lane & 15, hi = lane >> 4;
  const int wid = tid >> 6;
  const int wr = (wid >> 1) << 6, wc = (wid & 1) << 6;

  v4i acc[4][4] = {};
  v4i aK0[4], aK1[4], bK[4];

  const int nk = K >> 7, niter = nk >> 1, nkm = nk - 1;

  STG128(0, 0);
  VMC(0);
  BARRIER();
  LDA4_128(0, 0, aK0);

#pragma unroll 1
  for (int i = 0; i < niter; ++i) {
    const int tO = 2 * i + 1;
    const int tE = (2 * i + 2) & nkm;   // wraps once at the end, harmless
    // ---- tile 2i (buf0) ----
    LGK(4);
    BARRIER();
    STG128(1, tO);                       // stage odd tile -> buf1
    LDB4_128(0, 0); FENCE(); LDA4_128(0, 1, aK1);
    LGK(4);                              // drains aK0+bK, leaves aK1
    MFMA16(aK0);
    VMC(0);                              // buf1 staged (partner WG overlaps)
    BARRIER();
    LDB4_128(0, 1); FENCE(); LDA4_128(1, 0, aK0);
    LGK(4);                              // drains aK1+bK, leaves aK0'
    MFMA16(aK1);
    // ---- tile 2i+1 (buf1) ----
    LGK(4);
    BARRIER();
    STG128(0, tE);                       // stage next even tile -> buf0
    LDB4_128(1, 0); FENCE(); LDA4_128(1, 1, aK1);
    LGK(4);
    MFMA16(aK0);
    VMC(0);
    BARRIER();
    LDB4_128(1, 1); FENCE(); LDA4_128(0, 0, aK0);
    LGK(4);
    MFMA16(aK1);
  }

  VMC(0);

  const float sDeq = (pAw[0] * pAin[0]) / (QMAX * QMAX);
  if (MODE == 0) {
    const float sQ = QMAX / pAnext[0];
    signed char* O = reinterpret_cast<signed char*>(outp);
#pragma unroll
    for (int n = 0; n < 4; ++n) {
      int gcol = bcolBase + wc + n * 16 + l15;
      int bv = bias[gcol];
#pragma unroll
      for (int m = 0; m < 4; ++m) {
        int growb = browBase + wr + m * 16 + (hi << 2);
#pragma unroll
        for (int r = 0; r < 4; ++r) {
          float f = (float)(acc[m][n][r] + bv) * sDeq;
          f = fmaxf(f, 0.0f);
          float qf = fminf(fmaxf(rintf(f * sQ), -QMAX), QMAX);
          O[(size_t)(growb + r) * N + gcol] = (signed char)(int)qf;
        }
      }
    }
  } else {
    float* O = reinterpret_cast<float*>(outp);
#pragma unroll
    for (int n = 0; n < 4; ++n) {
      int gcol = bcolBase + wc + n * 16 + l15;
      int bv = bias[gcol];
#pragma unroll
      for (int m = 0; m < 4; ++m) {
        int growb = browBase + wr + m * 16 + (hi << 2);
#pragma unroll
        for (int r = 0; r < 4; ++r) {
          O[(size_t)(growb + r) * N + gcol] = (float)(acc[m][n][r] + bv) * sDeq;
        }
      }
    }
  }
}

extern "C" void kernel_launch(void* const* d_in, const int* in_sizes, int n_in,
                              void* d_out, int out_size, void* d_ws, size_t ws_size,
                              hipStream_t stream) {
  const float* x     = (const float*)d_in[0];
  const float* a_in0 = (const float*)d_in[1];
  const float* a_w0  = (const float*)d_in[2];
  const float* a_in2 = (const float*)d_in[3];
  const float* a_w2  = (const float*)d_in[4];
  const float* a_in4 = (const float*)d_in[5];
  const float* a_w4  = (const float*)d_in[6];
  const int*   W0    = (const int*)d_in[7];
  const int*   W1    = (const int*)d_in[8];
  const int*   W2    = (const int*)d_in[9];
  float* out = (float*)d_out;

  constexpr int B = 4096, IN = 1024, H0 = 4096, H1 = 4096, OUTN = 1024;

  char* ws = (char*)d_ws;
  size_t off = 0;
  auto alloc = [&](size_t sz) {
    char* p = ws + off;
    off += (sz + 255) & ~(size_t)255;
    return p;
  };
  signed char* qa0 = (signed char*)alloc((size_t)B * IN);
  signed char* qa1 = (signed char*)alloc((size_t)B * H0);
  signed char* qa2 = (signed char*)alloc((size_t)B * H1);
  signed char* W0p = (signed char*)alloc((size_t)H0 * IN);
  signed char* W1p = (signed char*)alloc((size_t)H1 * H0);
  signed char* W2p = (signed char*)alloc((size_t)OUTN * H1);
  int* b0 = (int*)alloc((size_t)H0 * 4);
  int* b1 = (int*)alloc((size_t)H1 * 4);
  int* b2 = (int*)alloc((size_t)OUTN * 4);

  // merged prep: pack W0/W1/W2 + quantize x (1 launch, 28672 blocks)
  prep_kernel<<<28672, 256, 0, stream>>>(x, qa0, a_in0,
                                         W0, W0p, b0,
                                         W1, W1p, b1,
                                         W2, W2p, b2);

  // layer 0: [B,IN]x[H0,IN]^T -> qa1 (int8), grid 32x32=1024 (4 WG-waves/CU)
  qgemm_kernel<0><<<(B / 128) * (H0 / 128), 256, 0, stream>>>(
      qa0, W0p, b0, qa1, H0, IN, H0 / 128, a_in0, a_w0, a_in2);

  // layer 1: [B,H0]x[H1,H0]^T -> qa2 (int8), grid 32x32=1024
  qgemm_kernel<0><<<(B / 128) * (H1 / 128), 256, 0, stream>>>(
      qa1, W1p, b1, qa2, H1, H0, H1 / 128, a_in2, a_w2, a_in4);

  // layer 2: [B,H1]x[OUT,H1]^T -> f32 out, grid 32x8=256
  qgemm_kernel<1><<<(B / 128) * (OUTN / 128), 256, 0, stream>>>(
      qa2, W2p, b2, out, OUTN, H1, OUTN / 128, a_in4, a_w4, a_in4);
}